// Round 13
// baseline (520.313 us; speedup 1.0000x reference)
//
#include <hip/hip_runtime.h>
#include <hip/hip_bf16.h>
#include <math.h>

// Problem constants
#define NB   1024   // batch
#define NT   60     // time steps
#define NC   10     // in channels
#define NDM  256    // d_model
#define NH   16     // heads
#define NDH  16     // per-head value dim
#define NA   13     // num attention queries
#define NM   208    // NA*NH
#define NMO  128    // MLP out

// weff6 row: 128 groups x 32 floats (128 B aligned); group g = d-pair (2g, 2g+1),
// slot dl*13+ak for dl in {0,1}; slots 26..31 pad. Row = 4096 floats.
#define WROW6 4096

// Workspace layout (floats)
#define OFF_WEFF  0
#define N_WEFF    (NH*14*WROW6)                // 917,504
#define OFF_BEFF  (OFF_WEFF + N_WEFF)
#define N_BEFF    (NM*NH*NA)                   // 43,264
#define OFF_VGT   (OFF_BEFF + N_BEFF)
#define N_VGT     (NB*NDM*64)                  // 16,777,216 (v transposed [b][d][64])
#define OFF_ATT   (OFF_VGT + N_VGT)
#define N_ATT     (NM*NB*NDH)                  // 3,407,872

#define LDS_FENCE() __asm__ __volatile__("s_waitcnt lgkmcnt(0)" ::: "memory")

// ---------------- K0: weff6[hk][mi][g][32], m = 13*hk+mi
__global__ void ltae_weff(const float* __restrict__ Q, const float* __restrict__ Wk,
                          const float* __restrict__ bk, float* __restrict__ weff6,
                          float* __restrict__ beff2) {
    int blk = blockIdx.x;            // hk*14 + mi
    int hk = blk / 14, mi = blk - hk*14;
    int m  = hk*13 + mi;
    int mc = m > 207 ? 207 : m;      // slot (15,13) provably never read
    int d = threadIdx.x;
    float q0 = Q[mc*4+0], q1 = Q[mc*4+1], q2 = Q[mc*4+2], q3 = Q[mc*4+3];
    int g = d >> 1, dl = d & 1;
    size_t base = (size_t)blk*WROW6 + g*32 + dl*13;
#pragma unroll
    for (int ak = 0; ak < NA; ++ak) {
        int e = (ak*16 + hk)*4;
        float w = q0*Wk[(size_t)(e+0)*NDM + d] + q1*Wk[(size_t)(e+1)*NDM + d]
                + q2*Wk[(size_t)(e+2)*NDM + d] + q3*Wk[(size_t)(e+3)*NDM + d];
        weff6[base + ak] = w;
    }
    if (dl == 1) {               // zero the 6 pad slots of this group
#pragma unroll
        for (int p = 26; p < 32; ++p) weff6[(size_t)blk*WROW6 + g*32 + p] = 0.f;
    }
    if (d < NA && m <= 207) {
        int e = (d*16 + hk)*4;
        beff2[(m*16 + hk)*NA + d] = q0*bk[e] + q1*bk[e+1] + q2*bk[e+2] + q3*bk[e+3];
    }
}

// ---------------- K1: conv 1x1 + GroupNorm -> vgT[b][d][64] (t-padded, coalesced)
#define VT_S 66
#define K1_LDS_BYTES ((NDM*VT_S + NT*NC)*4)

__launch_bounds__(1024, 8)
__global__ void ltae_convgn(const float* __restrict__ x, const float* __restrict__ Wc,
                            const float* __restrict__ bc, const float* __restrict__ gnw,
                            const float* __restrict__ gnb, float* __restrict__ vgT) {
    extern __shared__ float smem[];
    float* Vt = smem;
    float* xs = smem + NDM*VT_S;
    int b = blockIdx.x, tid = threadIdx.x;
    if (tid < NT*NC) xs[tid] = x[(size_t)b*NT*NC + tid];
    __syncthreads();
    {
        int d = tid >> 2, q = tid & 3;   // wave = 16 d = one GN group
        float wc[NC];
#pragma unroll
        for (int c = 0; c < NC; ++c) wc[c] = Wc[d*NC + c];
        float bcv = bc[d];
        float h[15];
        float s1 = 0.f, s2 = 0.f;
#pragma unroll
        for (int k = 0; k < 15; ++k) {
            int t = 15*q + k;
            float a = bcv;
#pragma unroll
            for (int c = 0; c < NC; ++c) a = fmaf(xs[t*NC + c], wc[c], a);
            h[k] = a; s1 += a; s2 += a*a;
        }
#pragma unroll
        for (int off = 1; off < 64; off <<= 1) {
            s1 += __shfl_xor(s1, off);
            s2 += __shfl_xor(s2, off);
        }
        float mean = s1 * (1.f/960.f);
        float var  = s2 * (1.f/960.f) - mean*mean;
        float rstd = rsqrtf(var + 1e-5f);
        float g = gnw[d], bb = gnb[d];
#pragma unroll
        for (int k = 0; k < 15; ++k)
            Vt[d*VT_S + 15*q + k] = (h[k]-mean)*rstd*g + bb;
    }
    __syncthreads();
    float* vb = vgT + (size_t)b*NDM*64;
    for (int i = tid; i < NDM*64; i += 1024) {
        int d = i >> 6, t = i & 63;
        vb[i] = (t < NT) ? Vt[d*VT_S + t] : 0.f;
    }
}

// ---------------- K2: scrambled attention; block = (b-group of 4, hk-quadrant)
// Weights via s_load (wave-uniform row, SGPR operands = zero per-FMA read cost),
// amortized over 4 consecutive b sharing the same mi. v via coalesced VMEM.
// acc[4][13] = 52 VGPRs. LDS: per-wave 784-float softmax slot only.
#define BSTRIDE (NDM*64)
__launch_bounds__(256, 5)
__global__ void ltae_attn(const float* __restrict__ vgT, const float* __restrict__ weff6,
                          const float* __restrict__ beff2, float* __restrict__ attout) {
    __shared__ float wbuf[4*784];        // 12,544 B
    int blk = blockIdx.x;                // bg*4 + q
    int bg = blk >> 2, q = blk & 3;
    int b0 = bg << 2;
    int tid = threadIdx.x;
    int wid = tid >> 6, lane = tid & 63;
    int hk = __builtin_amdgcn_readfirstlane(q*4 + wid);  // uniform -> scalar path
    int tk = lane;
    int mi0    = (13*b0) >> 10;                          // block-uniform
    int rstar0 = ((mi0+1) << 10) - 13*b0;                // switch for b0+jb iff rstar0-13jb < 13
    const float* __restrict__ wrow = weff6 + (size_t)(hk*14 + mi0)*WROW6;
    const float* __restrict__ vX   = vgT + (size_t)b0*BSTRIDE + tk;
    float* myC = wbuf + wid*784;

    float acc[4][13];
#pragma unroll
    for (int jb = 0; jb < 4; ++jb)
#pragma unroll
        for (int j = 0; j < 13; ++j) acc[jb][j] = 0.f;

    // ---- pass A: row (hk, mi0), 128 d-pair groups, shared across 4 b
#pragma unroll 1
    for (int g = 0; g < 128; ++g) {
        const float* wg = wrow + g*32;   // uniform -> s_load_dwordx16 pair
        float v0[4], v1[4];
#pragma unroll
        for (int jb = 0; jb < 4; ++jb) {
            v0[jb] = vX[jb*BSTRIDE + (2*g)*64];
            v1[jb] = vX[jb*BSTRIDE + (2*g+1)*64];
        }
#pragma unroll
        for (int jb = 0; jb < 4; ++jb)
#pragma unroll
            for (int ak = 0; ak < 13; ++ak)
                acc[jb][ak] = fmaf(v1[jb], wg[13+ak], fmaf(v0[jb], wg[ak], acc[jb][ak]));
    }

    // ---- pass B per b where needed: row (hk, mi0+1)
    // rstar_j <= 0  -> whole b_j on row mi0+1 (recompute all lanes)
    // 1..12        -> lanes tk>=tstar recompute; straddler lane bounces prefix via LDS
#pragma unroll 1
    for (int jb = 0; jb < 4; ++jb) {
        int rstar_j = rstar0 - 13*jb;
        if (rstar_j < 13) {
            int ustar = 60*rstar_j;
            int tstar = (ustar >= 1) ? (ustar/13) : -1;
            if (tk == tstar) {
#pragma unroll
                for (int j = 0; j < 13; ++j) myC[j] = acc[jb][j];
            }
            LDS_FENCE();
            if (tk >= tstar) {
#pragma unroll
                for (int j = 0; j < 13; ++j) acc[jb][j] = 0.f;
                const float* __restrict__ wrow2 = weff6 + (size_t)(hk*14 + mi0 + 1)*WROW6;
#pragma unroll 1
                for (int g = 0; g < 128; ++g) {
                    const float* wg = wrow2 + g*32;
                    float v0 = vX[jb*BSTRIDE + (2*g)*64];
                    float v1 = vX[jb*BSTRIDE + (2*g+1)*64];
#pragma unroll
                    for (int ak = 0; ak < 13; ++ak)
                        acc[jb][ak] = fmaf(v1, wg[13+ak], fmaf(v0, wg[ak], acc[jb][ak]));
                }
            }
            if (tk == tstar) {
#pragma unroll
                for (int j = 0; j < 13; ++j)
                    if (13*tk + j < ustar) acc[jb][j] = myC[j];
            }
            LDS_FENCE();
        }
    }

    // ---- softmax + AV per b (full 780-float wave slot; no phases)
    int dh = lane >> 2, cc = lane & 3;
#pragma unroll 1
    for (int jb = 0; jb < 4; ++jb) {
        int b = b0 + jb;
        int hb13 = (hk*1024 + b)*13;
        if (tk < NT) {
#pragma unroll
            for (int j = 0; j < 13; ++j) myC[13*tk + j] = acc[jb][j];
        }
        LDS_FENCE();
        float vreg[15];
#pragma unroll
        for (int j = 0; j < 15; ++j)
            vreg[j] = vgT[((size_t)b*NDM + hk*16 + dh)*64 + cc + 4*j];
        for (int r = 0; r < 13; ++r) {
            int n = hb13 + r;
            int m = n >> 10;                         // exact variant for this row
            int brow = (m*16 + hk)*13;
            float logit = -1e30f;
            if (lane < NT) {
                int u  = r*60 + lane;
                int ak = u % 13;
                logit = (myC[u] + beff2[brow + ak]) * 0.5f;
            }
            float mx = logit;
#pragma unroll
            for (int off = 32; off; off >>= 1) mx = fmaxf(mx, __shfl_xor(mx, off));
            float e = (lane < NT) ? __expf(logit - mx) : 0.f;
            float s = e;
#pragma unroll
            for (int off = 32; off; off >>= 1) s += __shfl_xor(s, off);
            float attn = e / s;
            if (lane < NT) myC[r*60 + lane] = attn;  // same-wave in-order LDS
            LDS_FENCE();
            float a = 0.f;
#pragma unroll
            for (int j = 0; j < 15; ++j)
                a = fmaf(myC[r*60 + cc + 4*j], vreg[j], a);
            a += __shfl_xor(a, 1);
            a += __shfl_xor(a, 2);
            if (cc == 0) attout[(size_t)n*NDH + dh] = a;
        }
        LDS_FENCE();
    }
}

// ---------------- K3: MLP + BN(eval) + ReLU + GroupNorm(16,128); 16 rows/block,
// each thread computes 2 rows per W1-row load.
__launch_bounds__(1024)
__global__ void ltae_mlp(const float* __restrict__ attout, const float* __restrict__ W1,
                         const float* __restrict__ b1, const float* __restrict__ bnw,
                         const float* __restrict__ bnb, const float* __restrict__ bnrm,
                         const float* __restrict__ bnrv, const float* __restrict__ gow,
                         const float* __restrict__ gob, float* __restrict__ out) {
    __shared__ float f[16][NDM];
    int tid = threadIdx.x;
    int sl  = tid >> 7;          // 0..7
    int j   = tid & 127;
    int base = blockIdx.x << 4;  // 16 sids per block; sid = a2*1024 + b2
    for (int k = tid; k < 16*NDM; k += 1024) {
        int s = k >> 8, c = k & 255;
        int sid2 = base + s;
        int aa = sid2 >> 10, bb = sid2 & 1023;
        int h2 = c >> 4, dhh = c & 15;
        f[s][c] = attout[((size_t)((aa*16 + h2)*1024 + bb))*NDH + dhh];
    }
    __syncthreads();
    const float* fr0 = f[sl];
    const float* fr1 = f[sl + 8];
    const float* w   = &W1[(size_t)j*NDM];
    float bj = b1[j];
    float acc0 = bj, acc1 = bj;
    for (int c = 0; c < NDM; c += 4) {
        float4 wv = *(const float4*)&w[c];
        acc0 += wv.x*fr0[c] + wv.y*fr0[c+1] + wv.z*fr0[c+2] + wv.w*fr0[c+3];
        acc1 += wv.x*fr1[c] + wv.y*fr1[c+1] + wv.z*fr1[c+2] + wv.w*fr1[c+3];
    }
    float rs = rsqrtf(bnrv[j] + 1e-5f);
    float sc = rs * bnw[j];
    float sh = bnb[j] - bnrm[j]*sc;
    float y0 = fmaxf(acc0*sc + sh, 0.f);
    float y1 = fmaxf(acc1*sc + sh, 0.f);
    float a1 = y0, b1s = y0*y0, a2 = y1, b2s = y1*y1;
#pragma unroll
    for (int off = 1; off < 8; off <<= 1) {
        a1  += __shfl_xor(a1, off);
        b1s += __shfl_xor(b1s, off);
        a2  += __shfl_xor(a2, off);
        b2s += __shfl_xor(b2s, off);
    }
    float gw = gow[j], gb = gob[j];
    {
        float mean = a1 * 0.125f;
        float var  = b1s * 0.125f - mean*mean;
        float o = (y0 - mean) * rsqrtf(var + 1e-5f) * gw + gb;
        int sid = base + sl, aa = sid >> 10, bb = sid & 1023;
        out[((size_t)bb*NA + aa)*NMO + j] = o;
    }
    {
        float mean = a2 * 0.125f;
        float var  = b2s * 0.125f - mean*mean;
        float o = (y1 - mean) * rsqrtf(var + 1e-5f) * gw + gb;
        int sid = base + sl + 8, aa = sid >> 10, bb = sid & 1023;
        out[((size_t)bb*NA + aa)*NMO + j] = o;
    }
}

extern "C" void kernel_launch(void* const* d_in, const int* in_sizes, int n_in,
                              void* d_out, int out_size, void* d_ws, size_t ws_size,
                              hipStream_t stream) {
    const float* x    = (const float*)d_in[0];
    const float* Wc   = (const float*)d_in[1];
    const float* bc   = (const float*)d_in[2];
    const float* gnw  = (const float*)d_in[3];
    const float* gnb  = (const float*)d_in[4];
    const float* Q    = (const float*)d_in[5];
    const float* Wk   = (const float*)d_in[6];
    const float* bk   = (const float*)d_in[7];
    const float* W1   = (const float*)d_in[8];
    const float* b1   = (const float*)d_in[9];
    const float* bnw  = (const float*)d_in[10];
    const float* bnb  = (const float*)d_in[11];
    const float* bnrm = (const float*)d_in[12];
    const float* bnrv = (const float*)d_in[13];
    const float* gow  = (const float*)d_in[14];
    const float* gob  = (const float*)d_in[15];

    float* ws     = (float*)d_ws;
    float* weff6  = ws + OFF_WEFF;
    float* beff2  = ws + OFF_BEFF;
    float* vgT    = ws + OFF_VGT;
    float* attout = ws + OFF_ATT;
    float* outp   = (float*)d_out;

    hipLaunchKernelGGL(ltae_weff, dim3(NH*14), dim3(256), 0, stream, Q, Wk, bk, weff6, beff2);
    hipFuncSetAttribute((const void*)ltae_convgn,
                        hipFuncAttributeMaxDynamicSharedMemorySize, K1_LDS_BYTES);
    hipLaunchKernelGGL(ltae_convgn, dim3(NB), dim3(1024), K1_LDS_BYTES, stream,
                       x, Wc, bc, gnw, gnb, vgT);
    hipLaunchKernelGGL(ltae_attn, dim3(NB), dim3(256), 0, stream,
                       vgT, weff6, beff2, attout);
    hipLaunchKernelGGL(ltae_mlp, dim3(NA*NB/16), dim3(1024), 0, stream,
                       attout, W1, b1, bnw, bnb, bnrm, bnrv, gow, gob, outp);
}

// Round 15
// 494.653 us; speedup vs baseline: 1.0519x; 1.0519x over previous
//
#include <hip/hip_runtime.h>
#include <hip/hip_bf16.h>
#include <math.h>

// Problem constants
#define NB   1024   // batch
#define NT   60     // time steps
#define NC   10     // in channels
#define NDM  256    // d_model
#define NH   16     // heads
#define NDH  16     // per-head value dim
#define NA   13     // num attention queries
#define NM   208    // NA*NH
#define NMO  128    // MLP out

// weff6 row: 128 groups x 32 floats (128 B aligned); group g = d-pair (2g, 2g+1),
// slot dl*13+ak for dl in {0,1}; slots 26..31 pad. Row = 4096 floats.
#define WROW6 4096

// Workspace layout (floats)
#define OFF_WEFF  0
#define N_WEFF    (NH*14*WROW6)                // 917,504
#define OFF_BEFF  (OFF_WEFF + N_WEFF)
#define N_BEFF    (NM*NH*NA)                   // 43,264
#define OFF_VGT   (OFF_BEFF + N_BEFF)
#define N_VGT     (NB*NDM*64)                  // 16,777,216 (v transposed [b][d][64])
#define OFF_ATT   (OFF_VGT + N_VGT)
#define N_ATT     (NM*NB*NDH)                  // 3,407,872

#define LDS_FENCE() __asm__ __volatile__("s_waitcnt lgkmcnt(0)" ::: "memory")

// ---------------- K0: weff6[hk][mi][g][32], m = 13*hk+mi
__global__ void ltae_weff(const float* __restrict__ Q, const float* __restrict__ Wk,
                          const float* __restrict__ bk, float* __restrict__ weff6,
                          float* __restrict__ beff2) {
    int blk = blockIdx.x;            // hk*14 + mi
    int hk = blk / 14, mi = blk - hk*14;
    int m  = hk*13 + mi;
    int mc = m > 207 ? 207 : m;      // slot (15,13) provably never read
    int d = threadIdx.x;
    float q0 = Q[mc*4+0], q1 = Q[mc*4+1], q2 = Q[mc*4+2], q3 = Q[mc*4+3];
    int g = d >> 1, dl = d & 1;
    size_t base = (size_t)blk*WROW6 + g*32 + dl*13;
#pragma unroll
    for (int ak = 0; ak < NA; ++ak) {
        int e = (ak*16 + hk)*4;
        float w = q0*Wk[(size_t)(e+0)*NDM + d] + q1*Wk[(size_t)(e+1)*NDM + d]
                + q2*Wk[(size_t)(e+2)*NDM + d] + q3*Wk[(size_t)(e+3)*NDM + d];
        weff6[base + ak] = w;
    }
    if (dl == 1) {               // zero the 6 pad slots of this group
#pragma unroll
        for (int p = 26; p < 32; ++p) weff6[(size_t)blk*WROW6 + g*32 + p] = 0.f;
    }
    if (d < NA && m <= 207) {
        int e = (d*16 + hk)*4;
        beff2[(m*16 + hk)*NA + d] = q0*bk[e] + q1*bk[e+1] + q2*bk[e+2] + q3*bk[e+3];
    }
}

// ---------------- K1: conv 1x1 + GroupNorm -> vgT[b][d][64] (t-padded, coalesced)
#define VT_S 66
#define K1_LDS_BYTES ((NDM*VT_S + NT*NC)*4)

__launch_bounds__(1024, 8)
__global__ void ltae_convgn(const float* __restrict__ x, const float* __restrict__ Wc,
                            const float* __restrict__ bc, const float* __restrict__ gnw,
                            const float* __restrict__ gnb, float* __restrict__ vgT) {
    extern __shared__ float smem[];
    float* Vt = smem;
    float* xs = smem + NDM*VT_S;
    int b = blockIdx.x, tid = threadIdx.x;
    if (tid < NT*NC) xs[tid] = x[(size_t)b*NT*NC + tid];
    __syncthreads();
    {
        int d = tid >> 2, q = tid & 3;   // wave = 16 d = one GN group
        float wc[NC];
#pragma unroll
        for (int c = 0; c < NC; ++c) wc[c] = Wc[d*NC + c];
        float bcv = bc[d];
        float h[15];
        float s1 = 0.f, s2 = 0.f;
#pragma unroll
        for (int k = 0; k < 15; ++k) {
            int t = 15*q + k;
            float a = bcv;
#pragma unroll
            for (int c = 0; c < NC; ++c) a = fmaf(xs[t*NC + c], wc[c], a);
            h[k] = a; s1 += a; s2 += a*a;
        }
#pragma unroll
        for (int off = 1; off < 64; off <<= 1) {
            s1 += __shfl_xor(s1, off);
            s2 += __shfl_xor(s2, off);
        }
        float mean = s1 * (1.f/960.f);
        float var  = s2 * (1.f/960.f) - mean*mean;
        float rstd = rsqrtf(var + 1e-5f);
        float g = gnw[d], bb = gnb[d];
#pragma unroll
        for (int k = 0; k < 15; ++k)
            Vt[d*VT_S + 15*q + k] = (h[k]-mean)*rstd*g + bb;
    }
    __syncthreads();
    float* vb = vgT + (size_t)b*NDM*64;
    for (int i = tid; i < NDM*64; i += 1024) {
        int d = i >> 6, t = i & 63;
        vb[i] = (t < NT) ? Vt[d*VT_S + t] : 0.f;
    }
}

// ---------------- K2: scrambled attention; block = (b-group of 4, hk-quadrant)
// Weights via s_load (wave-uniform row, SGPR operands), amortized over 4
// consecutive b sharing one weight row. v via coalesced VMEM. All acc indexing
// is compile-time-static (fully unrolled jb) so acc[4][13] stays in VGPRs.
#define BSTRIDE (NDM*64)
__launch_bounds__(256, 5)
__global__ void ltae_attn(const float* __restrict__ vgT, const float* __restrict__ weff6,
                          const float* __restrict__ beff2, float* __restrict__ attout) {
    __shared__ float wbuf[4*784];        // 12,544 B
    int blk = blockIdx.x;                // bg*4 + q
    int bg = blk >> 2, q = blk & 3;
    int b0 = bg << 2;
    int tid = threadIdx.x;
    int wid = tid >> 6, lane = tid & 63;
    int hk = __builtin_amdgcn_readfirstlane(q*4 + wid);  // uniform -> scalar path
    int tk = lane;
    int mi0    = (13*b0) >> 10;                          // block-uniform
    int rstar0 = ((mi0+1) << 10) - 13*b0;                // switch for b0+jb iff rstar0-13jb < 13
    const float* __restrict__ wrow = weff6 + (size_t)(hk*14 + mi0)*WROW6;
    const float* __restrict__ vX   = vgT + (size_t)b0*BSTRIDE + tk;
    float* myC = wbuf + wid*784;

    float acc[4][13];
#pragma unroll
    for (int jb = 0; jb < 4; ++jb)
#pragma unroll
        for (int j = 0; j < 13; ++j) acc[jb][j] = 0.f;

    // ---- pass A: row (hk, mi0), 128 d-pair groups, shared across 4 b
#pragma unroll 1
    for (int g = 0; g < 128; ++g) {
        const float* wg = wrow + g*32;   // uniform -> s_load_dwordx16 pair
        float v0[4], v1[4];
#pragma unroll
        for (int jb = 0; jb < 4; ++jb) {
            v0[jb] = vX[jb*BSTRIDE + (2*g)*64];
            v1[jb] = vX[jb*BSTRIDE + (2*g+1)*64];
        }
#pragma unroll
        for (int jb = 0; jb < 4; ++jb)
#pragma unroll
            for (int ak = 0; ak < 13; ++ak)
                acc[jb][ak] = fmaf(v1[jb], wg[13+ak], fmaf(v0[jb], wg[ak], acc[jb][ak]));
    }

    // ---- pass B per b where needed: row (hk, mi0+1). FULLY UNROLLED so acc
    // indexing stays static (dynamic indexing demotes acc to scratch — R13 bug).
#pragma unroll
    for (int jb = 0; jb < 4; ++jb) {
        int rstar_j = rstar0 - 13*jb;
        if (rstar_j < 13) {
            int ustar = 60*rstar_j;
            int tstar = (ustar >= 1) ? (ustar/13) : -1;
            if (tk == tstar) {
#pragma unroll
                for (int j = 0; j < 13; ++j) myC[j] = acc[jb][j];
            }
            LDS_FENCE();
            if (tk >= tstar) {
#pragma unroll
                for (int j = 0; j < 13; ++j) acc[jb][j] = 0.f;
                const float* __restrict__ wrow2 = weff6 + (size_t)(hk*14 + mi0 + 1)*WROW6;
#pragma unroll 1
                for (int g = 0; g < 128; ++g) {
                    const float* wg = wrow2 + g*32;
                    float v0 = vX[jb*BSTRIDE + (2*g)*64];
                    float v1 = vX[jb*BSTRIDE + (2*g+1)*64];
#pragma unroll
                    for (int ak = 0; ak < 13; ++ak)
                        acc[jb][ak] = fmaf(v1, wg[13+ak], fmaf(v0, wg[ak], acc[jb][ak]));
                }
            }
            if (tk == tstar) {
#pragma unroll
                for (int j = 0; j < 13; ++j)
                    if (13*tk + j < ustar) acc[jb][j] = myC[j];
            }
            LDS_FENCE();
        }
    }

    // ---- softmax + AV per b; FULLY UNROLLED jb (static acc indexing)
    int dh = lane >> 2, cc = lane & 3;
#pragma unroll
    for (int jb = 0; jb < 4; ++jb) {
        int b = b0 + jb;
        int hb13 = (hk*1024 + b)*13;
        if (tk < NT) {
#pragma unroll
            for (int j = 0; j < 13; ++j) myC[13*tk + j] = acc[jb][j];
        }
        LDS_FENCE();
        float vreg[15];
#pragma unroll
        for (int j = 0; j < 15; ++j)
            vreg[j] = vgT[((size_t)b*NDM + hk*16 + dh)*64 + cc + 4*j];
#pragma unroll 1
        for (int r = 0; r < 13; ++r) {
            int n = hb13 + r;
            int m = n >> 10;                         // exact variant for this row
            int brow = (m*16 + hk)*13;
            float logit = -1e30f;
            if (lane < NT) {
                int u  = r*60 + lane;
                int ak = u % 13;
                logit = (myC[u] + beff2[brow + ak]) * 0.5f;
            }
            float mx = logit;
#pragma unroll
            for (int off = 32; off; off >>= 1) mx = fmaxf(mx, __shfl_xor(mx, off));
            float e = (lane < NT) ? __expf(logit - mx) : 0.f;
            float s = e;
#pragma unroll
            for (int off = 32; off; off >>= 1) s += __shfl_xor(s, off);
            float attn = e / s;
            if (lane < NT) myC[r*60 + lane] = attn;  // same-wave in-order LDS
            LDS_FENCE();
            float a = 0.f;
#pragma unroll
            for (int j = 0; j < 15; ++j)
                a = fmaf(myC[r*60 + cc + 4*j], vreg[j], a);
            a += __shfl_xor(a, 1);
            a += __shfl_xor(a, 2);
            if (cc == 0) attout[(size_t)n*NDH + dh] = a;
        }
        LDS_FENCE();
    }
}

// ---------------- K3: MLP + BN(eval) + ReLU + GroupNorm(16,128); 16 rows/block,
// each thread computes 2 rows per W1-row load.
__launch_bounds__(1024)
__global__ void ltae_mlp(const float* __restrict__ attout, const float* __restrict__ W1,
                         const float* __restrict__ b1, const float* __restrict__ bnw,
                         const float* __restrict__ bnb, const float* __restrict__ bnrm,
                         const float* __restrict__ bnrv, const float* __restrict__ gow,
                         const float* __restrict__ gob, float* __restrict__ out) {
    __shared__ float f[16][NDM];
    int tid = threadIdx.x;
    int sl  = tid >> 7;          // 0..7
    int j   = tid & 127;
    int base = blockIdx.x << 4;  // 16 sids per block; sid = a2*1024 + b2
    for (int k = tid; k < 16*NDM; k += 1024) {
        int s = k >> 8, c = k & 255;
        int sid2 = base + s;
        int aa = sid2 >> 10, bb = sid2 & 1023;
        int h2 = c >> 4, dhh = c & 15;
        f[s][c] = attout[((size_t)((aa*16 + h2)*1024 + bb))*NDH + dhh];
    }
    __syncthreads();
    const float* fr0 = f[sl];
    const float* fr1 = f[sl + 8];
    const float* w   = &W1[(size_t)j*NDM];
    float bj = b1[j];
    float acc0 = bj, acc1 = bj;
    for (int c = 0; c < NDM; c += 4) {
        float4 wv = *(const float4*)&w[c];
        acc0 += wv.x*fr0[c] + wv.y*fr0[c+1] + wv.z*fr0[c+2] + wv.w*fr0[c+3];
        acc1 += wv.x*fr1[c] + wv.y*fr1[c+1] + wv.z*fr1[c+2] + wv.w*fr1[c+3];
    }
    float rs = rsqrtf(bnrv[j] + 1e-5f);
    float sc = rs * bnw[j];
    float sh = bnb[j] - bnrm[j]*sc;
    float y0 = fmaxf(acc0*sc + sh, 0.f);
    float y1 = fmaxf(acc1*sc + sh, 0.f);
    float a1 = y0, b1s = y0*y0, a2 = y1, b2s = y1*y1;
#pragma unroll
    for (int off = 1; off < 8; off <<= 1) {
        a1  += __shfl_xor(a1, off);
        b1s += __shfl_xor(b1s, off);
        a2  += __shfl_xor(a2, off);
        b2s += __shfl_xor(b2s, off);
    }
    float gw = gow[j], gb = gob[j];
    {
        float mean = a1 * 0.125f;
        float var  = b1s * 0.125f - mean*mean;
        float o = (y0 - mean) * rsqrtf(var + 1e-5f) * gw + gb;
        int sid = base + sl, aa = sid >> 10, bb = sid & 1023;
        out[((size_t)bb*NA + aa)*NMO + j] = o;
    }
    {
        float mean = a2 * 0.125f;
        float var  = b2s * 0.125f - mean*mean;
        float o = (y1 - mean) * rsqrtf(var + 1e-5f) * gw + gb;
        int sid = base + sl + 8, aa = sid >> 10, bb = sid & 1023;
        out[((size_t)bb*NA + aa)*NMO + j] = o;
    }
}

extern "C" void kernel_launch(void* const* d_in, const int* in_sizes, int n_in,
                              void* d_out, int out_size, void* d_ws, size_t ws_size,
                              hipStream_t stream) {
    const float* x    = (const float*)d_in[0];
    const float* Wc   = (const float*)d_in[1];
    const float* bc   = (const float*)d_in[2];
    const float* gnw  = (const float*)d_in[3];
    const float* gnb  = (const float*)d_in[4];
    const float* Q    = (const float*)d_in[5];
    const float* Wk   = (const float*)d_in[6];
    const float* bk   = (const float*)d_in[7];
    const float* W1   = (const float*)d_in[8];
    const float* b1   = (const float*)d_in[9];
    const float* bnw  = (const float*)d_in[10];
    const float* bnb  = (const float*)d_in[11];
    const float* bnrm = (const float*)d_in[12];
    const float* bnrv = (const float*)d_in[13];
    const float* gow  = (const float*)d_in[14];
    const float* gob  = (const float*)d_in[15];

    float* ws     = (float*)d_ws;
    float* weff6  = ws + OFF_WEFF;
    float* beff2  = ws + OFF_BEFF;
    float* vgT    = ws + OFF_VGT;
    float* attout = ws + OFF_ATT;
    float* outp   = (float*)d_out;

    hipLaunchKernelGGL(ltae_weff, dim3(NH*14), dim3(256), 0, stream, Q, Wk, bk, weff6, beff2);
    hipFuncSetAttribute((const void*)ltae_convgn,
                        hipFuncAttributeMaxDynamicSharedMemorySize, K1_LDS_BYTES);
    hipLaunchKernelGGL(ltae_convgn, dim3(NB), dim3(1024), K1_LDS_BYTES, stream,
                       x, Wc, bc, gnw, gnb, vgT);
    hipLaunchKernelGGL(ltae_attn, dim3(NB), dim3(256), 0, stream,
                       vgT, weff6, beff2, attout);
    hipLaunchKernelGGL(ltae_mlp, dim3(NA*NB/16), dim3(1024), 0, stream,
                       attout, W1, b1, bnw, bnb, bnrm, bnrv, gow, gob, outp);
}

// Round 16
// 423.309 us; speedup vs baseline: 1.2292x; 1.1685x over previous
//
#include <hip/hip_runtime.h>
#include <hip/hip_bf16.h>
#include <math.h>

// Problem constants
#define NB   1024   // batch
#define NT   60     // time steps
#define NC   10     // in channels
#define NDM  256    // d_model
#define NH   16     // heads
#define NDH  16     // per-head value dim
#define NA   13     // num attention queries
#define NM   208    // NA*NH
#define NMO  128    // MLP out

// weff6 row: 128 groups x 32 floats (128 B aligned); group g = d-pair (2g, 2g+1),
// slot dl*13+ak for dl in {0,1}; slots 26..31 pad. Row = 4096 floats.
#define WROW6 4096

// Workspace layout (floats)
#define OFF_WEFF  0
#define N_WEFF    (NH*14*WROW6)                // 917,504
#define OFF_BEFF  (OFF_WEFF + N_WEFF)
#define N_BEFF    (NM*NH*NA)                   // 43,264
#define OFF_VGT   (OFF_BEFF + N_BEFF)
#define N_VGT     (NB*NDM*64)                  // 16,777,216 (v transposed [b][d][64])
#define OFF_ATT   (OFF_VGT + N_VGT)
#define N_ATT     (NM*NB*NDH)                  // 3,407,872

#define LDS_FENCE() __asm__ __volatile__("s_waitcnt lgkmcnt(0)" ::: "memory")

// ---------------- K0: weff6[hk][mi][g][32], m = 13*hk+mi
__global__ void ltae_weff(const float* __restrict__ Q, const float* __restrict__ Wk,
                          const float* __restrict__ bk, float* __restrict__ weff6,
                          float* __restrict__ beff2) {
    int blk = blockIdx.x;            // hk*14 + mi
    int hk = blk / 14, mi = blk - hk*14;
    int m  = hk*13 + mi;
    int mc = m > 207 ? 207 : m;      // slot (15,13) provably never read
    int d = threadIdx.x;
    float q0 = Q[mc*4+0], q1 = Q[mc*4+1], q2 = Q[mc*4+2], q3 = Q[mc*4+3];
    int g = d >> 1, dl = d & 1;
    size_t base = (size_t)blk*WROW6 + g*32 + dl*13;
#pragma unroll
    for (int ak = 0; ak < NA; ++ak) {
        int e = (ak*16 + hk)*4;
        float w = q0*Wk[(size_t)(e+0)*NDM + d] + q1*Wk[(size_t)(e+1)*NDM + d]
                + q2*Wk[(size_t)(e+2)*NDM + d] + q3*Wk[(size_t)(e+3)*NDM + d];
        weff6[base + ak] = w;
    }
    if (dl == 1) {               // zero the 6 pad slots of this group
#pragma unroll
        for (int p = 26; p < 32; ++p) weff6[(size_t)blk*WROW6 + g*32 + p] = 0.f;
    }
    if (d < NA && m <= 207) {
        int e = (d*16 + hk)*4;
        beff2[(m*16 + hk)*NA + d] = q0*bk[e] + q1*bk[e+1] + q2*bk[e+2] + q3*bk[e+3];
    }
}

// ---------------- K1: conv 1x1 + GroupNorm -> vgT[b][d][64] (t-padded, coalesced)
#define VT_S 66
#define K1_LDS_BYTES ((NDM*VT_S + NT*NC)*4)

__launch_bounds__(1024, 8)
__global__ void ltae_convgn(const float* __restrict__ x, const float* __restrict__ Wc,
                            const float* __restrict__ bc, const float* __restrict__ gnw,
                            const float* __restrict__ gnb, float* __restrict__ vgT) {
    extern __shared__ float smem[];
    float* Vt = smem;
    float* xs = smem + NDM*VT_S;
    int b = blockIdx.x, tid = threadIdx.x;
    if (tid < NT*NC) xs[tid] = x[(size_t)b*NT*NC + tid];
    __syncthreads();
    {
        int d = tid >> 2, q = tid & 3;   // wave = 16 d = one GN group
        float wc[NC];
#pragma unroll
        for (int c = 0; c < NC; ++c) wc[c] = Wc[d*NC + c];
        float bcv = bc[d];
        float h[15];
        float s1 = 0.f, s2 = 0.f;
#pragma unroll
        for (int k = 0; k < 15; ++k) {
            int t = 15*q + k;
            float a = bcv;
#pragma unroll
            for (int c = 0; c < NC; ++c) a = fmaf(xs[t*NC + c], wc[c], a);
            h[k] = a; s1 += a; s2 += a*a;
        }
#pragma unroll
        for (int off = 1; off < 64; off <<= 1) {
            s1 += __shfl_xor(s1, off);
            s2 += __shfl_xor(s2, off);
        }
        float mean = s1 * (1.f/960.f);
        float var  = s2 * (1.f/960.f) - mean*mean;
        float rstd = rsqrtf(var + 1e-5f);
        float g = gnw[d], bb = gnb[d];
#pragma unroll
        for (int k = 0; k < 15; ++k)
            Vt[d*VT_S + 15*q + k] = (h[k]-mean)*rstd*g + bb;
    }
    __syncthreads();
    float* vb = vgT + (size_t)b*NDM*64;
    for (int i = tid; i < NDM*64; i += 1024) {
        int d = i >> 6, t = i & 63;
        vb[i] = (t < NT) ? Vt[d*VT_S + t] : 0.f;
    }
}

// ---------------- K2: scrambled attention; block = (b-pair, hk-quadrant)
// Weights via s_load (wave-uniform row, SGPR operands), amortized over 2
// consecutive b sharing one weight row — balances work-per-lgkm-drain (~110 cyc)
// against wave count (2048 blocks -> 6 blocks/CU = 24 waves/CU).
#define BSTRIDE (NDM*64)
__launch_bounds__(256, 6)
__global__ void ltae_attn(const float* __restrict__ vgT, const float* __restrict__ weff6,
                          const float* __restrict__ beff2, float* __restrict__ attout) {
    __shared__ float wbuf[4*784];        // 12,544 B
    int blk = blockIdx.x;                // bg*4 + q
    int bg = blk >> 2, q = blk & 3;
    int b0 = bg << 1;                    // 2 b per block
    int tid = threadIdx.x;
    int wid = tid >> 6, lane = tid & 63;
    int hk = __builtin_amdgcn_readfirstlane(q*4 + wid);  // uniform -> scalar path
    int tk = lane;
    int mi0    = (13*b0) >> 10;                          // block-uniform
    int rstar0 = ((mi0+1) << 10) - 13*b0;                // switch for b0+jb iff rstar0-13jb < 13
    const float* __restrict__ wrow = weff6 + (size_t)(hk*14 + mi0)*WROW6;
    const float* __restrict__ vX   = vgT + (size_t)b0*BSTRIDE + tk;
    float* myC = wbuf + wid*784;

    float acc[2][13];
#pragma unroll
    for (int jb = 0; jb < 2; ++jb)
#pragma unroll
        for (int j = 0; j < 13; ++j) acc[jb][j] = 0.f;

    // ---- pass A: row (hk, mi0), 128 d-pair groups, shared across 2 b
#pragma unroll 1
    for (int g = 0; g < 128; ++g) {
        const float* wg = wrow + g*32;   // uniform -> s_load_dwordx16 pair
        float v0[2], v1[2];
#pragma unroll
        for (int jb = 0; jb < 2; ++jb) {
            v0[jb] = vX[jb*BSTRIDE + (2*g)*64];
            v1[jb] = vX[jb*BSTRIDE + (2*g+1)*64];
        }
#pragma unroll
        for (int jb = 0; jb < 2; ++jb)
#pragma unroll
            for (int ak = 0; ak < 13; ++ak)
                acc[jb][ak] = fmaf(v1[jb], wg[13+ak], fmaf(v0[jb], wg[ak], acc[jb][ak]));
    }

    // ---- pass B per b where needed: row (hk, mi0+1). FULLY UNROLLED so acc
    // indexing stays static (dynamic indexing demotes acc to scratch — R13 bug).
#pragma unroll
    for (int jb = 0; jb < 2; ++jb) {
        int rstar_j = rstar0 - 13*jb;
        if (rstar_j < 13) {
            int ustar = 60*rstar_j;
            int tstar = (ustar >= 1) ? (ustar/13) : -1;
            if (tk == tstar) {
#pragma unroll
                for (int j = 0; j < 13; ++j) myC[j] = acc[jb][j];
            }
            LDS_FENCE();
            if (tk >= tstar) {
#pragma unroll
                for (int j = 0; j < 13; ++j) acc[jb][j] = 0.f;
                const float* __restrict__ wrow2 = weff6 + (size_t)(hk*14 + mi0 + 1)*WROW6;
#pragma unroll 1
                for (int g = 0; g < 128; ++g) {
                    const float* wg = wrow2 + g*32;
                    float v0 = vX[jb*BSTRIDE + (2*g)*64];
                    float v1 = vX[jb*BSTRIDE + (2*g+1)*64];
#pragma unroll
                    for (int ak = 0; ak < 13; ++ak)
                        acc[jb][ak] = fmaf(v1, wg[13+ak], fmaf(v0, wg[ak], acc[jb][ak]));
                }
            }
            if (tk == tstar) {
#pragma unroll
                for (int j = 0; j < 13; ++j)
                    if (13*tk + j < ustar) acc[jb][j] = myC[j];
            }
            LDS_FENCE();
        }
    }

    // ---- softmax + AV per b; FULLY UNROLLED jb (static acc indexing)
    int dh = lane >> 2, cc = lane & 3;
#pragma unroll
    for (int jb = 0; jb < 2; ++jb) {
        int b = b0 + jb;
        int hb13 = (hk*1024 + b)*13;
        if (tk < NT) {
#pragma unroll
            for (int j = 0; j < 13; ++j) myC[13*tk + j] = acc[jb][j];
        }
        LDS_FENCE();
        float vreg[15];
#pragma unroll
        for (int j = 0; j < 15; ++j)
            vreg[j] = vgT[((size_t)b*NDM + hk*16 + dh)*64 + cc + 4*j];
#pragma unroll 1
        for (int r = 0; r < 13; ++r) {
            int n = hb13 + r;
            int m = n >> 10;                         // exact variant for this row
            int brow = (m*16 + hk)*13;
            float logit = -1e30f;
            if (lane < NT) {
                int u  = r*60 + lane;
                int ak = u % 13;
                logit = (myC[u] + beff2[brow + ak]) * 0.5f;
            }
            float mx = logit;
#pragma unroll
            for (int off = 32; off; off >>= 1) mx = fmaxf(mx, __shfl_xor(mx, off));
            float e = (lane < NT) ? __expf(logit - mx) : 0.f;
            float s = e;
#pragma unroll
            for (int off = 32; off; off >>= 1) s += __shfl_xor(s, off);
            float attn = e / s;
            if (lane < NT) myC[r*60 + lane] = attn;  // same-wave in-order LDS
            LDS_FENCE();
            float a = 0.f;
#pragma unroll
            for (int j = 0; j < 15; ++j)
                a = fmaf(myC[r*60 + cc + 4*j], vreg[j], a);
            a += __shfl_xor(a, 1);
            a += __shfl_xor(a, 2);
            if (cc == 0) attout[(size_t)n*NDH + dh] = a;
        }
        LDS_FENCE();
    }
}

// ---------------- K3: MLP + BN(eval) + ReLU + GroupNorm(16,128); 16 rows/block,
// each thread computes 2 rows per W1-row load.
__launch_bounds__(1024)
__global__ void ltae_mlp(const float* __restrict__ attout, const float* __restrict__ W1,
                         const float* __restrict__ b1, const float* __restrict__ bnw,
                         const float* __restrict__ bnb, const float* __restrict__ bnrm,
                         const float* __restrict__ bnrv, const float* __restrict__ gow,
                         const float* __restrict__ gob, float* __restrict__ out) {
    __shared__ float f[16][NDM];
    int tid = threadIdx.x;
    int sl  = tid >> 7;          // 0..7
    int j   = tid & 127;
    int base = blockIdx.x << 4;  // 16 sids per block; sid = a2*1024 + b2
    for (int k = tid; k < 16*NDM; k += 1024) {
        int s = k >> 8, c = k & 255;
        int sid2 = base + s;
        int aa = sid2 >> 10, bb = sid2 & 1023;
        int h2 = c >> 4, dhh = c & 15;
        f[s][c] = attout[((size_t)((aa*16 + h2)*1024 + bb))*NDH + dhh];
    }
    __syncthreads();
    const float* fr0 = f[sl];
    const float* fr1 = f[sl + 8];
    const float* w   = &W1[(size_t)j*NDM];
    float bj = b1[j];
    float acc0 = bj, acc1 = bj;
    for (int c = 0; c < NDM; c += 4) {
        float4 wv = *(const float4*)&w[c];
        acc0 += wv.x*fr0[c] + wv.y*fr0[c+1] + wv.z*fr0[c+2] + wv.w*fr0[c+3];
        acc1 += wv.x*fr1[c] + wv.y*fr1[c+1] + wv.z*fr1[c+2] + wv.w*fr1[c+3];
    }
    float rs = rsqrtf(bnrv[j] + 1e-5f);
    float sc = rs * bnw[j];
    float sh = bnb[j] - bnrm[j]*sc;
    float y0 = fmaxf(acc0*sc + sh, 0.f);
    float y1 = fmaxf(acc1*sc + sh, 0.f);
    float a1 = y0, b1s = y0*y0, a2 = y1, b2s = y1*y1;
#pragma unroll
    for (int off = 1; off < 8; off <<= 1) {
        a1  += __shfl_xor(a1, off);
        b1s += __shfl_xor(b1s, off);
        a2  += __shfl_xor(a2, off);
        b2s += __shfl_xor(b2s, off);
    }
    float gw = gow[j], gb = gob[j];
    {
        float mean = a1 * 0.125f;
        float var  = b1s * 0.125f - mean*mean;
        float o = (y0 - mean) * rsqrtf(var + 1e-5f) * gw + gb;
        int sid = base + sl, aa = sid >> 10, bb = sid & 1023;
        out[((size_t)bb*NA + aa)*NMO + j] = o;
    }
    {
        float mean = a2 * 0.125f;
        float var  = b2s * 0.125f - mean*mean;
        float o = (y1 - mean) * rsqrtf(var + 1e-5f) * gw + gb;
        int sid = base + sl + 8, aa = sid >> 10, bb = sid & 1023;
        out[((size_t)bb*NA + aa)*NMO + j] = o;
    }
}

extern "C" void kernel_launch(void* const* d_in, const int* in_sizes, int n_in,
                              void* d_out, int out_size, void* d_ws, size_t ws_size,
                              hipStream_t stream) {
    const float* x    = (const float*)d_in[0];
    const float* Wc   = (const float*)d_in[1];
    const float* bc   = (const float*)d_in[2];
    const float* gnw  = (const float*)d_in[3];
    const float* gnb  = (const float*)d_in[4];
    const float* Q    = (const float*)d_in[5];
    const float* Wk   = (const float*)d_in[6];
    const float* bk   = (const float*)d_in[7];
    const float* W1   = (const float*)d_in[8];
    const float* b1   = (const float*)d_in[9];
    const float* bnw  = (const float*)d_in[10];
    const float* bnb  = (const float*)d_in[11];
    const float* bnrm = (const float*)d_in[12];
    const float* bnrv = (const float*)d_in[13];
    const float* gow  = (const float*)d_in[14];
    const float* gob  = (const float*)d_in[15];

    float* ws     = (float*)d_ws;
    float* weff6  = ws + OFF_WEFF;
    float* beff2  = ws + OFF_BEFF;
    float* vgT    = ws + OFF_VGT;
    float* attout = ws + OFF_ATT;
    float* outp   = (float*)d_out;

    hipLaunchKernelGGL(ltae_weff, dim3(NH*14), dim3(256), 0, stream, Q, Wk, bk, weff6, beff2);
    hipFuncSetAttribute((const void*)ltae_convgn,
                        hipFuncAttributeMaxDynamicSharedMemorySize, K1_LDS_BYTES);
    hipLaunchKernelGGL(ltae_convgn, dim3(NB), dim3(1024), K1_LDS_BYTES, stream,
                       x, Wc, bc, gnw, gnb, vgT);
    hipLaunchKernelGGL(ltae_attn, dim3(NB/2*4), dim3(256), 0, stream,
                       vgT, weff6, beff2, attout);
    hipLaunchKernelGGL(ltae_mlp, dim3(NA*NB/16), dim3(1024), 0, stream,
                       attout, W1, b1, bnw, bnb, bnrm, bnrv, gow, gob, outp);
}